// Round 11
// baseline (1062.646 us; speedup 1.0000x reference)
//
#include <hip/hip_runtime.h>
#include <hip/hip_bf16.h>
#include <math.h>

static constexpr int N = 50000;
static constexpr int E = 800000;
static constexpr int F = 128;
static constexpr int H = 64;
static constexpr int G = 512;
static constexpr int C = 10;
static constexpr int CAP = 256;    // per-graph capacity for 24-bit-tied edges (~1-3 expected)

static inline int cdiv(long a, int b) { return (int)((a + b - 1) / b); }

__device__ __forceinline__ float uinv_score(unsigned u) {
  // inverse of the order-preserving float->uint map
  return (u & 0x80000000u) ? __uint_as_float(u & 0x7fffffffu) : __uint_as_float(~u);
}

// ---- deg (in-deg over dst) + goff boundary detection (fused) ----
__global__ void k_deg_goff(const int* __restrict__ dst, const int* __restrict__ batch,
                           int* __restrict__ deg, int* __restrict__ goff) {
  for (int i = blockIdx.x * 256 + threadIdx.x; i < N; i += gridDim.x * 256) {
    int b = batch[i];
    if (i == 0) {
      for (int g = 0; g <= b; ++g) goff[g] = 0;
    } else {
      int p = batch[i - 1];
      for (int g = p + 1; g <= b; ++g) goff[g] = i;
    }
    if (i == N - 1) {
      for (int g = b + 1; g <= G; ++g) goff[g] = N;
    }
  }
  for (int e = blockIdx.x * 256 + threadIdx.x; e < E; e += gridDim.x * 256)
    atomicAdd(&deg[dst[e]], 1);
}

// ---- parallel exclusive scan, 3 kernels ----
__global__ void k_scan_a(const int* __restrict__ cnt, int* __restrict__ off,
                         int* __restrict__ bsum, int n) {
  __shared__ int wsum[16];
  int tid = threadIdx.x, lane = tid & 63, wv = tid >> 6;
  int idx = blockIdx.x * 4096 + tid * 4;
  int v0 = (idx + 0 < n) ? cnt[idx + 0] : 0;
  int v1 = (idx + 1 < n) ? cnt[idx + 1] : 0;
  int v2 = (idx + 2 < n) ? cnt[idx + 2] : 0;
  int v3 = (idx + 3 < n) ? cnt[idx + 3] : 0;
  int local = v0 + v1 + v2 + v3;
  int inc = local;
  for (int d = 1; d < 64; d <<= 1) {
    int t = __shfl_up(inc, d);
    if (lane >= d) inc += t;
  }
  if (lane == 63) wsum[wv] = inc;
  __syncthreads();
  if (tid < 16) {
    int t = wsum[tid];
    for (int d = 1; d < 16; d <<= 1) {
      int u = __shfl_up(t, d);
      if (tid >= d) t += u;
    }
    wsum[tid] = t;
  }
  __syncthreads();
  int woff = (wv > 0) ? wsum[wv - 1] : 0;
  int excl = woff + inc - local;
  if (idx + 0 < n) off[idx + 0] = excl;
  if (idx + 1 < n) off[idx + 1] = excl + v0;
  if (idx + 2 < n) off[idx + 2] = excl + v0 + v1;
  if (idx + 3 < n) off[idx + 3] = excl + v0 + v1 + v2;
  if (tid == 0) bsum[blockIdx.x] = wsum[15];
}

__global__ void k_scan_b(int* __restrict__ bsum, int nb) {   // 1 wave
  int lane = threadIdx.x;
  int v = (lane < nb) ? bsum[lane] : 0;
  int inc = v;
  for (int d = 1; d < 64; d <<= 1) {
    int t = __shfl_up(inc, d);
    if (lane >= d) inc += t;
  }
  if (lane < nb) bsum[lane] = inc - v;      // exclusive
  if (lane == nb) bsum[nb] = inc;           // total
}

__global__ void k_scan_c(int* __restrict__ off, int* __restrict__ cursor,
                         const int* __restrict__ bsum, int n, int nb) {
  int i = blockIdx.x * 256 + threadIdx.x;
  if (i < n) {
    int v = off[i] + bsum[i >> 12];
    off[i] = v;
    cursor[i] = v;
  } else if (i == n) {
    off[n] = bsum[nb];
  }
}

// ---- windowed counting-sort fill: only dst in [lo,hi) this pass ----
__global__ void k_fill_csr(const int* __restrict__ src, const int* __restrict__ dst,
                           int* __restrict__ cursor, int2* __restrict__ csr,
                           int* __restrict__ einv, int lo, int hi) {
  int e = blockIdx.x * 256 + threadIdx.x;
  if (e >= E) return;
  int d = dst[e];
  if (d < lo || d >= hi) return;
  int slot = atomicAdd(&cursor[d], 1);
  csr[slot] = make_int2(src[e], e);
  einv[e] = slot;
}

// ---- dense pre-GEMM (fp32 y): y = in@Wl, r = in@Wr + b ----
template <int K>
__global__ void k_gemm2(const float* __restrict__ in, const float* __restrict__ Wl,
                        const float* __restrict__ Wr, const float* __restrict__ b,
                        float* __restrict__ y, float* __restrict__ r) {
  __shared__ float sx[16][K];
  int lane = threadIdx.x, ty = threadIdx.y;
  int tid = ty * 64 + lane;
  int row0 = blockIdx.x * 16;
  const float4* gsrc = (const float4*)(in + (size_t)row0 * K);
  float4* sdst = (float4*)(&sx[0][0]);
#pragma unroll
  for (int i = tid; i < 16 * K / 4; i += 256) sdst[i] = gsrc[i];
  __syncthreads();
  float al[4], ar[4];
  float bias = b[lane];
#pragma unroll
  for (int j = 0; j < 4; ++j) { al[j] = 0.f; ar[j] = bias; }
#pragma unroll 4
  for (int f = 0; f < K; ++f) {
    float wl = Wl[f * H + lane];
    float wr = Wr[f * H + lane];
#pragma unroll
    for (int j = 0; j < 4; ++j) {
      float xv = sx[ty * 4 + j][f];
      al[j] += xv * wl;
      ar[j] += xv * wr;
    }
  }
#pragma unroll
  for (int j = 0; j < 4; ++j) {
    int row = row0 + ty * 4 + j;
    y[(size_t)row * H + lane] = al[j];
    r[(size_t)row * H + lane] = ar[j];
  }
}

// ---- dense pre-GEMM (bf16 y table): layers 2/3 ----
template <int K>
__global__ void k_gemm2h(const float* __restrict__ in, const float* __restrict__ Wl,
                         const float* __restrict__ Wr, const float* __restrict__ b,
                         __hip_bfloat16* __restrict__ y, float* __restrict__ r) {
  __shared__ float sx[16][K];
  int lane = threadIdx.x, ty = threadIdx.y;
  int tid = ty * 64 + lane;
  int row0 = blockIdx.x * 16;
  const float4* gsrc = (const float4*)(in + (size_t)row0 * K);
  float4* sdst = (float4*)(&sx[0][0]);
#pragma unroll
  for (int i = tid; i < 16 * K / 4; i += 256) sdst[i] = gsrc[i];
  __syncthreads();
  float al[4], ar[4];
  float bias = b[lane];
#pragma unroll
  for (int j = 0; j < 4; ++j) { al[j] = 0.f; ar[j] = bias; }
#pragma unroll 4
  for (int f = 0; f < K; ++f) {
    float wl = Wl[f * H + lane];
    float wr = Wr[f * H + lane];
#pragma unroll
    for (int j = 0; j < 4; ++j) {
      float xv = sx[ty * 4 + j][f];
      al[j] += xv * wl;
      ar[j] += xv * wr;
    }
  }
#pragma unroll
  for (int j = 0; j < 4; ++j) {
    int row = row0 + ty * 4 + j;
    y[(size_t)row * H + lane] = __float2bfloat16(al[j]);
    r[(size_t)row * H + lane] = ar[j];
  }
}

// ---- layer-1 aggregation (fp32 rows): eighth-wave per edge ----
__global__ void k_agg1(const float* __restrict__ y, const float* __restrict__ r,
                       const int2* __restrict__ csr, const int* __restrict__ off,
                       float* __restrict__ out) {
  int node = blockIdx.x * 8 + threadIdx.y;
  int lane = threadIdx.x;
  int q = lane >> 3, c = lane & 7;
  int s0 = off[node], s1 = off[node + 1];
  float4 a0 = make_float4(0.f, 0.f, 0.f, 0.f);
  float4 a1 = make_float4(0.f, 0.f, 0.f, 0.f);
  int i = s0 + q;
  for (; i + 8 < s1; i += 16) {
    int2 se0 = csr[i];
    int2 se1 = csr[i + 8];
    const float4* p0 = (const float4*)(y + (size_t)se0.x * H);
    const float4* p1 = (const float4*)(y + (size_t)se1.x * H);
    float4 u0 = p0[c], v0 = p0[c + 8];
    float4 u1 = p1[c], v1 = p1[c + 8];
    a0.x += u0.x + u1.x; a0.y += u0.y + u1.y; a0.z += u0.z + u1.z; a0.w += u0.w + u1.w;
    a1.x += v0.x + v1.x; a1.y += v0.y + v1.y; a1.z += v0.z + v1.z; a1.w += v0.w + v1.w;
  }
  for (; i < s1; i += 8) {
    int2 se = csr[i];
    const float4* p = (const float4*)(y + (size_t)se.x * H);
    float4 u = p[c], v = p[c + 8];
    a0.x += u.x; a0.y += u.y; a0.z += u.z; a0.w += u.w;
    a1.x += v.x; a1.y += v.y; a1.z += v.z; a1.w += v.w;
  }
#pragma unroll
  for (int d = 8; d < 64; d <<= 1) {
    a0.x += __shfl_xor(a0.x, d); a0.y += __shfl_xor(a0.y, d);
    a0.z += __shfl_xor(a0.z, d); a0.w += __shfl_xor(a0.w, d);
    a1.x += __shfl_xor(a1.x, d); a1.y += __shfl_xor(a1.y, d);
    a1.z += __shfl_xor(a1.z, d); a1.w += __shfl_xor(a1.w, d);
  }
  if (q == 0) {
    float inv = 1.f / fmaxf((float)(s1 - s0), 1.f);
    const float4* rp = (const float4*)(r + (size_t)node * H);
    float4 r0 = rp[c], r1 = rp[c + 8];
    float4 o0, o1;
    o0.x = fmaxf(a0.x * inv + r0.x, 0.f); o0.y = fmaxf(a0.y * inv + r0.y, 0.f);
    o0.z = fmaxf(a0.z * inv + r0.z, 0.f); o0.w = fmaxf(a0.w * inv + r0.w, 0.f);
    o1.x = fmaxf(a1.x * inv + r1.x, 0.f); o1.y = fmaxf(a1.y * inv + r1.y, 0.f);
    o1.z = fmaxf(a1.z * inv + r1.z, 0.f); o1.w = fmaxf(a1.w * inv + r1.w, 0.f);
    float4* op = (float4*)(out + (size_t)node * H);
    op[c] = o0; op[c + 8] = o1;
  }
}

// ---- compact selected edges: one wave per node, ballot compaction.
// csr2[j] = {src, w_as_int}; off2/cnt2 per node; cross-node order arbitrary.
__global__ void k_compact(const unsigned char* __restrict__ sel,
                          const int2* __restrict__ csr, const float* __restrict__ ewc,
                          const int* __restrict__ off, int* __restrict__ cursor2,
                          int2* __restrict__ csr2, int* __restrict__ off2,
                          int* __restrict__ cnt2) {
  int node = blockIdx.x * 8 + threadIdx.y;
  int lane = threadIdx.x;
  int s0 = off[node], s1 = off[node + 1];
  unsigned long long lt = ((unsigned long long)1 << lane) - 1;
  int c = 0;
  for (int i = s0 + lane; i < s1; i += 64) c += sel[i] ? 1 : 0;
#pragma unroll
  for (int d = 1; d < 64; d <<= 1) c += __shfl_xor(c, d);   // total in all lanes
  int base = 0;
  if (lane == 0) {
    base = atomicAdd(cursor2, c);
    off2[node] = base;
    cnt2[node] = c;
  }
  base = __shfl(base, 0);
  int cum = 0;
  for (int i0 = s0; i0 < s1; i0 += 64) {
    int i = i0 + lane;
    bool f = (i < s1) && sel[i];
    unsigned long long m = __ballot(f);
    if (f) {
      int rank = __popcll(m & lt);
      int2 se = csr[i];
      csr2[base + cum + rank] = make_int2(se.x, __float_as_int(ewc[i]));
    }
    cum += __popcll(m);
  }
}

// ---- weighted aggregation over COMPACTED edges (bf16 rows): eighth-wave ----
__global__ void k_agg_w(const __hip_bfloat16* __restrict__ y, const float* __restrict__ r,
                        const int2* __restrict__ csr2, const int* __restrict__ off2,
                        const int* __restrict__ cnt2, const int* __restrict__ off,
                        float* __restrict__ out) {
  int node = blockIdx.x * 8 + threadIdx.y;
  int lane = threadIdx.x;
  int q = lane >> 3, c = lane & 7;
  int b0 = off2[node], cn = cnt2[node];
  float a[8] = {0.f, 0.f, 0.f, 0.f, 0.f, 0.f, 0.f, 0.f};
  for (int j = q; j < cn; j += 8) {
    int2 sw = csr2[b0 + j];
    float w = __int_as_float(sw.y);
    uint4 pk = ((const uint4*)((const unsigned short*)y + (size_t)sw.x * H))[c];
    a[0] += w * __uint_as_float(pk.x << 16); a[1] += w * __uint_as_float(pk.x & 0xffff0000u);
    a[2] += w * __uint_as_float(pk.y << 16); a[3] += w * __uint_as_float(pk.y & 0xffff0000u);
    a[4] += w * __uint_as_float(pk.z << 16); a[5] += w * __uint_as_float(pk.z & 0xffff0000u);
    a[6] += w * __uint_as_float(pk.w << 16); a[7] += w * __uint_as_float(pk.w & 0xffff0000u);
  }
#pragma unroll
  for (int d = 8; d < 64; d <<= 1) {
#pragma unroll
    for (int j = 0; j < 8; ++j) a[j] += __shfl_xor(a[j], d);
  }
  if (q == 0) {
    int degn = off[node + 1] - off[node];
    float inv = 1.f / fmaxf((float)degn, 1.f);
    const float4* rp = (const float4*)(r + (size_t)node * H);
    float4 r0 = rp[2 * c], r1 = rp[2 * c + 1];
    float4 o0, o1;
    o0.x = fmaxf(a[0] * inv + r0.x, 0.f); o0.y = fmaxf(a[1] * inv + r0.y, 0.f);
    o0.z = fmaxf(a[2] * inv + r0.z, 0.f); o0.w = fmaxf(a[3] * inv + r0.w, 0.f);
    o1.x = fmaxf(a[4] * inv + r1.x, 0.f); o1.y = fmaxf(a[5] * inv + r1.y, 0.f);
    o1.z = fmaxf(a[6] * inv + r1.z, 0.f); o1.w = fmaxf(a[7] * inv + r1.w, 0.f);
    float4* op = (float4*)(out + (size_t)node * H);
    op[2 * c] = o0; op[2 * c + 1] = o1;
  }
}

// ---- node-major edge scoring in CSR order (x2 edge ILP) ----
__global__ void k_score_csr(const float* __restrict__ h1, const int2* __restrict__ csr,
                            const int* __restrict__ off, const int* __restrict__ batch,
                            unsigned* __restrict__ scoreu_csr,
                            unsigned short* __restrict__ seg_csr, int* __restrict__ hist) {
  int node = blockIdx.x * 8 + threadIdx.y;
  int lane = threadIdx.x;
  int q = lane >> 4, c = lane & 15;   // 4 quarters x 16 lanes; 16 x float4 = 256B row
  int s0 = off[node], s1 = off[node + 1];
  float4 hn = ((const float4*)(h1 + (size_t)node * H))[c];
  int i = s0 + q;
  for (; i + 4 < s1; i += 8) {
    int2 se0 = csr[i];
    int2 se1 = csr[i + 4];
    float4 hs0 = ((const float4*)(h1 + (size_t)se0.x * H))[c];
    float4 hs1 = ((const float4*)(h1 + (size_t)se1.x * H))[c];
    float p0 = hn.x * hs0.x + hn.y * hs0.y + hn.z * hs0.z + hn.w * hs0.w;
    float p1 = hn.x * hs1.x + hn.y * hs1.y + hn.z * hs1.z + hn.w * hs1.w;
    p0 += __shfl_xor(p0, 1); p1 += __shfl_xor(p1, 1);
    p0 += __shfl_xor(p0, 2); p1 += __shfl_xor(p1, 2);
    p0 += __shfl_xor(p0, 4); p1 += __shfl_xor(p1, 4);
    p0 += __shfl_xor(p0, 8); p1 += __shfl_xor(p1, 8);
    if (c == 0) {
      int g0 = batch[se0.x], g1 = batch[se1.x];
      unsigned u0 = __float_as_uint(p0); u0 = (u0 & 0x80000000u) ? ~u0 : (u0 | 0x80000000u);
      unsigned u1 = __float_as_uint(p1); u1 = (u1 & 0x80000000u) ? ~u1 : (u1 | 0x80000000u);
      scoreu_csr[i] = u0; scoreu_csr[i + 4] = u1;
      seg_csr[i] = (unsigned short)g0; seg_csr[i + 4] = (unsigned short)g1;
      atomicAdd(&hist[g0 * 256 + (int)(u0 >> 24)], 1);
      atomicAdd(&hist[g1 * 256 + (int)(u1 >> 24)], 1);
    }
  }
  for (; i < s1; i += 4) {
    int2 se = csr[i];
    float4 hs = ((const float4*)(h1 + (size_t)se.x * H))[c];
    float p = hn.x * hs.x + hn.y * hs.y + hn.z * hs.z + hn.w * hs.w;
    p += __shfl_xor(p, 1);
    p += __shfl_xor(p, 2);
    p += __shfl_xor(p, 4);
    p += __shfl_xor(p, 8);
    if (c == 0) {
      int g = batch[se.x];
      unsigned u = __float_as_uint(p);
      u = (u & 0x80000000u) ? ~u : (u | 0x80000000u);
      scoreu_csr[i] = u;
      seg_csr[i] = (unsigned short)g;
      atomicAdd(&hist[g * 256 + (int)(u >> 24)], 1);
    }
  }
}

// ---- radix-select histogram for passes 1..2 ----
__global__ void k_hist(const unsigned* __restrict__ scoreu, const unsigned short* __restrict__ seg,
                       const unsigned* __restrict__ prefix, int* __restrict__ hist, int pass) {
  int e = blockIdx.x * 256 + threadIdx.x;
  if (e >= E) return;
  unsigned u = scoreu[e];
  int g = (int)seg[e];
  int predshift = 32 - 8 * pass;
  if ((u >> predshift) == (prefix[g] >> predshift))
    atomicAdd(&hist[g * 256 + (int)((u >> (24 - 8 * pass)) & 0xFFu)], 1);
}

// ---- descending bucket select: one wave per graph; m from hist row sum ----
__global__ void k_scan(int* __restrict__ hist, unsigned* __restrict__ prefix,
                       int* __restrict__ krem, int pass) {
  int g = blockIdx.x;
  int lane = threadIdx.x;
  int4* row = (int4*)(hist + (size_t)g * 256);
  int4 v = row[lane];
  int vj[4] = {v.x, v.y, v.z, v.w};
  int s = v.x + v.y + v.z + v.w;
  int inc = s;
  for (int d = 1; d < 64; d <<= 1) {
    int t = __shfl_up(inc, d);
    if (lane >= d) inc += t;
  }
  int T = __shfl(inc, 63);
  int k = (pass == 0) ? ((T + 1) >> 1) : krem[g];   // pass 0: T = edges in graph
  int excl = inc - s;
  int pre[4] = {excl, excl + vj[0], excl + vj[0] + vj[1], excl + vj[0] + vj[1] + vj[2]};
  int bsel_l = -1, newk_l = 0;
  if (k > 0) {
    for (int j = 3; j >= 0; --j) {
      int suf = T - pre[j];
      if (suf >= k) { bsel_l = 4 * lane + j; newk_l = k - (suf - vj[j]); break; }
    }
  }
  unsigned long long mask = __ballot(bsel_l >= 0);
  int bsel = 255, newk = 0;
  if (k > 0 && mask) {
    int hi = 63 - __builtin_clzll(mask);
    bsel = __shfl(bsel_l, hi);
    newk = __shfl(newk_l, hi);
  }
  if (lane == 0) {
    unsigned base = (pass == 0) ? 0u : prefix[g];
    prefix[g] = base | ((unsigned)bsel << (24 - 8 * pass));
    krem[g] = newk;
  }
  row[lane] = make_int4(0, 0, 0, 0);
}

// ---- classify CSR slots vs 24-bit threshold ----
__global__ void k_select(const unsigned* __restrict__ scoreu_csr,
                         const unsigned short* __restrict__ seg_csr,
                         const unsigned* __restrict__ thresh,
                         int* __restrict__ eqcnt, int* __restrict__ eqlist,
                         unsigned char* __restrict__ sel_csr, float* __restrict__ ew_csr) {
  int s = blockIdx.x * 256 + threadIdx.x;
  if (s >= E) return;
  unsigned u = scoreu_csr[s];
  int g = (int)seg_csr[s];
  unsigned t = thresh[g];                 // top-24 bits, low 8 zero
  unsigned um = u & 0xffffff00u;
  float sel = 0.f;
  if (um > t) sel = 1.f;
  else if (um == t) {
    int slot = atomicAdd(&eqcnt[g], 1);
    if (slot < CAP) eqlist[g * CAP + slot] = s;
  }
  sel_csr[s] = (unsigned char)sel;
  ew_csr[s] = uinv_score(u) * sel;
}

// ---- resolve 24-bit ties: top-r by (score desc, original idx asc); r,c ~1-3 ----
__global__ void k_resolve(const int* __restrict__ krem, const int* __restrict__ eqcnt,
                          const int* __restrict__ eqlist, const int2* __restrict__ csr,
                          const unsigned* __restrict__ scoreu_csr,
                          unsigned char* __restrict__ sel_csr, float* __restrict__ ew_csr) {
  int g = blockIdx.x * 256 + threadIdx.x;
  if (g >= G) return;
  int c = eqcnt[g]; if (c > CAP) c = CAP;
  int r = krem[g];  if (r > c) r = c;
  const int* lst = eqlist + g * CAP;
  unsigned last_u = 0u; int last_e = -1; bool first = true;
  for (int i = 0; i < r; ++i) {
    unsigned bu = 0u; int be = -1, bs = -1;
    for (int j = 0; j < c; ++j) {
      int slot = lst[j];
      unsigned u = scoreu_csr[slot];
      int eid = csr[slot].y;
      bool after = first || (u < last_u) || (u == last_u && eid > last_e);
      if (after && (bs < 0 || u > bu || (u == bu && eid < be))) { bu = u; be = eid; bs = slot; }
    }
    if (bs < 0) break;
    sel_csr[bs] = 1;
    ew_csr[bs] = uinv_score(bu);
    last_u = bu; last_e = be; first = false;
  }
}

// ---- back-permute selection flags to edge order (output), x4 vectorized ----
__global__ void k_sampled(const int* __restrict__ einv, const unsigned char* __restrict__ sel_csr,
                          float* __restrict__ sampled) {
  int e = (blockIdx.x * 256 + threadIdx.x) * 4;
  if (e >= E) return;
  int4 iv = *(const int4*)(einv + e);
  float4 o;
  o.x = (float)sel_csr[iv.x];
  o.y = (float)sel_csr[iv.y];
  o.z = (float)sel_csr[iv.z];
  o.w = (float)sel_csr[iv.w];
  *(float4*)(sampled + e) = o;
}

// ---- fused mean-pool + MLP head + log_softmax: one block per graph ----
__global__ void k_poolhead(const float* __restrict__ h3, const int* __restrict__ goff,
                           const float* __restrict__ W1, const float* __restrict__ b1,
                           const float* __restrict__ W2, const float* __restrict__ b2,
                           float* __restrict__ outp) {
  int g = blockIdx.x;
  int h = threadIdx.x;
  int s0 = goff[g], s1 = goff[g + 1];
  float a = 0.f;
  for (int n = s0; n < s1; ++n) a += h3[(size_t)n * H + h];
  float inv = 1.f / fmaxf((float)(s1 - s0), 1.f);
  __shared__ float p[H], z1[H], z2[C];
  __shared__ float lse;
  p[h] = a * inv;
  __syncthreads();
  float acc = b1[h];
#pragma unroll 8
  for (int f = 0; f < H; ++f) acc += p[f] * W1[f * H + h];
  z1[h] = fmaxf(acc, 0.f);
  __syncthreads();
  if (h < C) {
    float a2 = b2[h];
#pragma unroll 8
    for (int f = 0; f < H; ++f) a2 += z1[f] * W2[f * C + h];
    z2[h] = a2;
  }
  __syncthreads();
  if (h == 0) {
    float m = z2[0];
    for (int c = 1; c < C; ++c) m = fmaxf(m, z2[c]);
    float s = 0.f;
    for (int c = 0; c < C; ++c) s += expf(z2[c] - m);
    lse = m + logf(s);
  }
  __syncthreads();
  if (h < C) outp[(size_t)g * C + h] = z2[h] - lse;
}

extern "C" void kernel_launch(void* const* d_in, const int* in_sizes, int n_in,
                              void* d_out, int out_size, void* d_ws, size_t ws_size,
                              hipStream_t stream) {
  const float* x     = (const float*)d_in[0];
  const int*   ei    = (const int*)d_in[1];
  const int*   batch = (const int*)d_in[2];
  const float* W1l   = (const float*)d_in[3];
  const float* b1l   = (const float*)d_in[4];
  const float* W1r   = (const float*)d_in[5];
  const float* W2l   = (const float*)d_in[6];
  const float* b2l   = (const float*)d_in[7];
  const float* W2r   = (const float*)d_in[8];
  const float* W3l   = (const float*)d_in[9];
  const float* b3l   = (const float*)d_in[10];
  const float* W3r   = (const float*)d_in[11];
  const float* Wlin1 = (const float*)d_in[12];
  const float* blin1 = (const float*)d_in[13];
  const float* Wlin2 = (const float*)d_in[14];
  const float* blin2 = (const float*)d_in[15];

  const int* srcv = ei;        // edge_index row 0
  const int* dstv = ei + E;    // edge_index row 1

  float* out_ls   = (float*)d_out;       // 512*10 log_softmax
  float* out_samp = out_ls + G * C;      // 800000 sampled mask

  // ---- workspace carve (256B-aligned); zero-init block first, one memset ----
  char* w = (char*)d_ws;
  auto carve = [&](size_t bytes) { void* p = (void*)w; w += (bytes + 255) & ~(size_t)255; return p; };
  char* zbase   = w;
  int*      deg     = (int*)carve((size_t)N * 4);
  int*      eqcnt   = (int*)carve((size_t)G * 4);
  int*      cursor2 = (int*)carve(256);                   // compaction cursor
  int*      hist    = (int*)carve((size_t)G * 256 * 4);
  size_t    zbytes  = (size_t)(w - zbase);
  float*    h1      = (float*)carve((size_t)N * H * 4);
  float*    h2      = (float*)carve((size_t)N * H * 4);
  float*    h3      = (float*)carve((size_t)N * H * 4);
  float*    yb      = (float*)carve((size_t)N * H * 4);   // fp32 projected-left (layer 1)
  float*    rb      = (float*)carve((size_t)N * H * 4);   // fp32 projected-right
  __hip_bfloat16* ybh = (__hip_bfloat16*)carve((size_t)N * H * 2);  // bf16 table (layers 2/3)
  unsigned* scoreu_csr = (unsigned*)carve((size_t)E * 4);
  unsigned short* seg_csr = (unsigned short*)carve((size_t)E * 2);
  float*    ew_csr     = (float*)carve((size_t)E * 4);
  unsigned char* sel_csr = (unsigned char*)carve((size_t)E);
  int2*     csr     = (int2*)carve((size_t)E * 8);        // {src, eid} per slot
  int*      einv    = (int*)carve((size_t)E * 4);         // edge -> slot
  int*      off     = (int*)carve((size_t)(N + 1) * 4);
  int*      cursor  = (int*)carve((size_t)N * 4);
  int*      off2    = (int*)carve((size_t)N * 4);
  int*      cnt2    = (int*)carve((size_t)N * 4);
  int*      goff    = (int*)carve((size_t)(G + 1) * 4);
  unsigned* prefix  = (unsigned*)carve((size_t)G * 4);
  int*      krem    = (int*)carve((size_t)G * 4);
  int*      eqlist  = (int*)carve((size_t)G * CAP * 4);
  int*      bsum    = (int*)carve((size_t)16 * 4);
  int2*     csr2    = (int2*)yb;   // overlay: yb dead after k_agg1; E/2 int2 fits in N*H*4

  hipMemsetAsync(zbase, 0, zbytes, stream);

  // ---- deg + goff, parallel scan, 2-window CSR fill ----
  k_deg_goff<<<128, 256, 0, stream>>>(dstv, batch, deg, goff);
  int nb = cdiv(N, 4096);   // 13
  k_scan_a<<<nb, 1024, 0, stream>>>(deg, off, bsum, N);
  k_scan_b<<<1, 64, 0, stream>>>(bsum, nb);
  k_scan_c<<<cdiv(N + 1, 256), 256, 0, stream>>>(off, cursor, bsum, N, nb);
  k_fill_csr<<<cdiv(E, 256), 256, 0, stream>>>(srcv, dstv, cursor, csr, einv, 0, N / 2);
  k_fill_csr<<<cdiv(E, 256), 256, 0, stream>>>(srcv, dstv, cursor, csr, einv, N / 2, N);

  // ---- layer 1: dense projections then fp32 gather ----
  k_gemm2<F><<<N / 16, dim3(64, 4), 0, stream>>>(x, W1l, W1r, b1l, yb, rb);
  k_agg1<<<N / 8, dim3(64, 8), 0, stream>>>(yb, rb, csr, off, h1);

  // ---- edge scores (CSR order) + 3-pass radix top-k (24-bit threshold) ----
  k_score_csr<<<N / 8, dim3(64, 8), 0, stream>>>(h1, csr, off, batch,
                                                 scoreu_csr, seg_csr, hist);
  k_scan<<<G, 64, 0, stream>>>(hist, prefix, krem, 0);
  for (int p = 1; p <= 2; ++p) {
    k_hist<<<cdiv(E, 256), 256, 0, stream>>>(scoreu_csr, seg_csr, prefix, hist, p);
    k_scan<<<G, 64, 0, stream>>>(hist, prefix, krem, p);
  }
  k_select<<<cdiv(E, 256), 256, 0, stream>>>(scoreu_csr, seg_csr, prefix,
                                             eqcnt, eqlist, sel_csr, ew_csr);
  k_resolve<<<cdiv(G, 256), 256, 0, stream>>>(krem, eqcnt, eqlist, csr, scoreu_csr,
                                              sel_csr, ew_csr);
  k_sampled<<<cdiv(E / 4, 256), 256, 0, stream>>>(einv, sel_csr, out_samp);

  // ---- compact selected edges (overlays dead yb) ----
  k_compact<<<N / 8, dim3(64, 8), 0, stream>>>(sel_csr, csr, ew_csr, off, cursor2,
                                               csr2, off2, cnt2);

  // ---- layer 2: projections (bf16 gather table) + compacted weighted gather ----
  k_gemm2h<H><<<N / 16, dim3(64, 4), 0, stream>>>(h1, W2l, W2r, b2l, ybh, rb);
  k_agg_w<<<N / 8, dim3(64, 8), 0, stream>>>(ybh, rb, csr2, off2, cnt2, off, h2);

  // ---- layer 3 ----
  k_gemm2h<H><<<N / 16, dim3(64, 4), 0, stream>>>(h2, W3l, W3r, b3l, ybh, rb);
  k_agg_w<<<N / 8, dim3(64, 8), 0, stream>>>(ybh, rb, csr2, off2, cnt2, off, h3);

  // ---- fused pool + head ----
  k_poolhead<<<G, 64, 0, stream>>>(h3, goff, Wlin1, blin1, Wlin2, blin2, out_ls);
}

// Round 12
// 497.128 us; speedup vs baseline: 2.1376x; 2.1376x over previous
//
#include <hip/hip_runtime.h>
#include <hip/hip_bf16.h>
#include <math.h>

static constexpr int N = 50000;
static constexpr int E = 800000;
static constexpr int F = 128;
static constexpr int H = 64;
static constexpr int G = 512;
static constexpr int C = 10;
static constexpr int CAP = 256;    // per-graph capacity for 24-bit-tied edges (~1-3 expected)

static inline int cdiv(long a, int b) { return (int)((a + b - 1) / b); }

__device__ __forceinline__ float uinv_score(unsigned u) {
  // inverse of the order-preserving float->uint map
  return (u & 0x80000000u) ? __uint_as_float(u & 0x7fffffffu) : __uint_as_float(~u);
}

// ---- deg (in-deg over dst) + goff boundary detection (fused) ----
__global__ void k_deg_goff(const int* __restrict__ dst, const int* __restrict__ batch,
                           int* __restrict__ deg, int* __restrict__ goff) {
  for (int i = blockIdx.x * 256 + threadIdx.x; i < N; i += gridDim.x * 256) {
    int b = batch[i];
    if (i == 0) {
      for (int g = 0; g <= b; ++g) goff[g] = 0;
    } else {
      int p = batch[i - 1];
      for (int g = p + 1; g <= b; ++g) goff[g] = i;
    }
    if (i == N - 1) {
      for (int g = b + 1; g <= G; ++g) goff[g] = N;
    }
  }
  for (int e = blockIdx.x * 256 + threadIdx.x; e < E; e += gridDim.x * 256)
    atomicAdd(&deg[dst[e]], 1);
}

// ---- parallel exclusive scan, 3 kernels ----
__global__ void k_scan_a(const int* __restrict__ cnt, int* __restrict__ off,
                         int* __restrict__ bsum, int n) {
  __shared__ int wsum[16];
  int tid = threadIdx.x, lane = tid & 63, wv = tid >> 6;
  int idx = blockIdx.x * 4096 + tid * 4;
  int v0 = (idx + 0 < n) ? cnt[idx + 0] : 0;
  int v1 = (idx + 1 < n) ? cnt[idx + 1] : 0;
  int v2 = (idx + 2 < n) ? cnt[idx + 2] : 0;
  int v3 = (idx + 3 < n) ? cnt[idx + 3] : 0;
  int local = v0 + v1 + v2 + v3;
  int inc = local;
  for (int d = 1; d < 64; d <<= 1) {
    int t = __shfl_up(inc, d);
    if (lane >= d) inc += t;
  }
  if (lane == 63) wsum[wv] = inc;
  __syncthreads();
  if (tid < 16) {
    int t = wsum[tid];
    for (int d = 1; d < 16; d <<= 1) {
      int u = __shfl_up(t, d);
      if (tid >= d) t += u;
    }
    wsum[tid] = t;
  }
  __syncthreads();
  int woff = (wv > 0) ? wsum[wv - 1] : 0;
  int excl = woff + inc - local;
  if (idx + 0 < n) off[idx + 0] = excl;
  if (idx + 1 < n) off[idx + 1] = excl + v0;
  if (idx + 2 < n) off[idx + 2] = excl + v0 + v1;
  if (idx + 3 < n) off[idx + 3] = excl + v0 + v1 + v2;
  if (tid == 0) bsum[blockIdx.x] = wsum[15];
}

__global__ void k_scan_b(int* __restrict__ bsum, int nb) {   // 1 wave
  int lane = threadIdx.x;
  int v = (lane < nb) ? bsum[lane] : 0;
  int inc = v;
  for (int d = 1; d < 64; d <<= 1) {
    int t = __shfl_up(inc, d);
    if (lane >= d) inc += t;
  }
  if (lane < nb) bsum[lane] = inc - v;      // exclusive
  if (lane == nb) bsum[nb] = inc;           // total
}

__global__ void k_scan_c(int* __restrict__ off, int* __restrict__ cursor,
                         const int* __restrict__ bsum, int n, int nb) {
  int i = blockIdx.x * 256 + threadIdx.x;
  if (i < n) {
    int v = off[i] + bsum[i >> 12];
    off[i] = v;
    cursor[i] = v;
  } else if (i == n) {
    off[n] = bsum[nb];
  }
}

// ---- windowed counting-sort fill: only dst in [lo,hi) this pass ----
__global__ void k_fill_csr(const int* __restrict__ src, const int* __restrict__ dst,
                           int* __restrict__ cursor, int2* __restrict__ csr,
                           int* __restrict__ einv, int lo, int hi) {
  int e = blockIdx.x * 256 + threadIdx.x;
  if (e >= E) return;
  int d = dst[e];
  if (d < lo || d >= hi) return;
  int slot = atomicAdd(&cursor[d], 1);
  csr[slot] = make_int2(src[e], e);
  einv[e] = slot;
}

// ---- dense pre-GEMM (fp32 y): y = in@Wl, r = in@Wr + b ----
template <int K>
__global__ void k_gemm2(const float* __restrict__ in, const float* __restrict__ Wl,
                        const float* __restrict__ Wr, const float* __restrict__ b,
                        float* __restrict__ y, float* __restrict__ r) {
  __shared__ float sx[16][K];
  int lane = threadIdx.x, ty = threadIdx.y;
  int tid = ty * 64 + lane;
  int row0 = blockIdx.x * 16;
  const float4* gsrc = (const float4*)(in + (size_t)row0 * K);
  float4* sdst = (float4*)(&sx[0][0]);
#pragma unroll
  for (int i = tid; i < 16 * K / 4; i += 256) sdst[i] = gsrc[i];
  __syncthreads();
  float al[4], ar[4];
  float bias = b[lane];
#pragma unroll
  for (int j = 0; j < 4; ++j) { al[j] = 0.f; ar[j] = bias; }
#pragma unroll 4
  for (int f = 0; f < K; ++f) {
    float wl = Wl[f * H + lane];
    float wr = Wr[f * H + lane];
#pragma unroll
    for (int j = 0; j < 4; ++j) {
      float xv = sx[ty * 4 + j][f];
      al[j] += xv * wl;
      ar[j] += xv * wr;
    }
  }
#pragma unroll
  for (int j = 0; j < 4; ++j) {
    int row = row0 + ty * 4 + j;
    y[(size_t)row * H + lane] = al[j];
    r[(size_t)row * H + lane] = ar[j];
  }
}

// ---- dense pre-GEMM (bf16 y table): layers 2/3 ----
template <int K>
__global__ void k_gemm2h(const float* __restrict__ in, const float* __restrict__ Wl,
                         const float* __restrict__ Wr, const float* __restrict__ b,
                         __hip_bfloat16* __restrict__ y, float* __restrict__ r) {
  __shared__ float sx[16][K];
  int lane = threadIdx.x, ty = threadIdx.y;
  int tid = ty * 64 + lane;
  int row0 = blockIdx.x * 16;
  const float4* gsrc = (const float4*)(in + (size_t)row0 * K);
  float4* sdst = (float4*)(&sx[0][0]);
#pragma unroll
  for (int i = tid; i < 16 * K / 4; i += 256) sdst[i] = gsrc[i];
  __syncthreads();
  float al[4], ar[4];
  float bias = b[lane];
#pragma unroll
  for (int j = 0; j < 4; ++j) { al[j] = 0.f; ar[j] = bias; }
#pragma unroll 4
  for (int f = 0; f < K; ++f) {
    float wl = Wl[f * H + lane];
    float wr = Wr[f * H + lane];
#pragma unroll
    for (int j = 0; j < 4; ++j) {
      float xv = sx[ty * 4 + j][f];
      al[j] += xv * wl;
      ar[j] += xv * wr;
    }
  }
#pragma unroll
  for (int j = 0; j < 4; ++j) {
    int row = row0 + ty * 4 + j;
    y[(size_t)row * H + lane] = __float2bfloat16(al[j]);
    r[(size_t)row * H + lane] = ar[j];
  }
}

// ---- layer-1 aggregation (fp32 rows): eighth-wave per edge ----
__global__ void k_agg1(const float* __restrict__ y, const float* __restrict__ r,
                       const int2* __restrict__ csr, const int* __restrict__ off,
                       float* __restrict__ out) {
  int node = blockIdx.x * 8 + threadIdx.y;
  int lane = threadIdx.x;
  int q = lane >> 3, c = lane & 7;
  int s0 = off[node], s1 = off[node + 1];
  float4 a0 = make_float4(0.f, 0.f, 0.f, 0.f);
  float4 a1 = make_float4(0.f, 0.f, 0.f, 0.f);
  int i = s0 + q;
  for (; i + 8 < s1; i += 16) {
    int2 se0 = csr[i];
    int2 se1 = csr[i + 8];
    const float4* p0 = (const float4*)(y + (size_t)se0.x * H);
    const float4* p1 = (const float4*)(y + (size_t)se1.x * H);
    float4 u0 = p0[c], v0 = p0[c + 8];
    float4 u1 = p1[c], v1 = p1[c + 8];
    a0.x += u0.x + u1.x; a0.y += u0.y + u1.y; a0.z += u0.z + u1.z; a0.w += u0.w + u1.w;
    a1.x += v0.x + v1.x; a1.y += v0.y + v1.y; a1.z += v0.z + v1.z; a1.w += v0.w + v1.w;
  }
  for (; i < s1; i += 8) {
    int2 se = csr[i];
    const float4* p = (const float4*)(y + (size_t)se.x * H);
    float4 u = p[c], v = p[c + 8];
    a0.x += u.x; a0.y += u.y; a0.z += u.z; a0.w += u.w;
    a1.x += v.x; a1.y += v.y; a1.z += v.z; a1.w += v.w;
  }
#pragma unroll
  for (int d = 8; d < 64; d <<= 1) {
    a0.x += __shfl_xor(a0.x, d); a0.y += __shfl_xor(a0.y, d);
    a0.z += __shfl_xor(a0.z, d); a0.w += __shfl_xor(a0.w, d);
    a1.x += __shfl_xor(a1.x, d); a1.y += __shfl_xor(a1.y, d);
    a1.z += __shfl_xor(a1.z, d); a1.w += __shfl_xor(a1.w, d);
  }
  if (q == 0) {
    float inv = 1.f / fmaxf((float)(s1 - s0), 1.f);
    const float4* rp = (const float4*)(r + (size_t)node * H);
    float4 r0 = rp[c], r1 = rp[c + 8];
    float4 o0, o1;
    o0.x = fmaxf(a0.x * inv + r0.x, 0.f); o0.y = fmaxf(a0.y * inv + r0.y, 0.f);
    o0.z = fmaxf(a0.z * inv + r0.z, 0.f); o0.w = fmaxf(a0.w * inv + r0.w, 0.f);
    o1.x = fmaxf(a1.x * inv + r1.x, 0.f); o1.y = fmaxf(a1.y * inv + r1.y, 0.f);
    o1.z = fmaxf(a1.z * inv + r1.z, 0.f); o1.w = fmaxf(a1.w * inv + r1.w, 0.f);
    float4* op = (float4*)(out + (size_t)node * H);
    op[c] = o0; op[c + 8] = o1;
  }
}

// ---- compact selected edges IN PLACE per node: base = off[node], no atomics.
// csr2[off[node]+j] = {src, w_as_int} for j-th selected edge of node.
__global__ void k_compact(const unsigned char* __restrict__ sel,
                          const int2* __restrict__ csr, const float* __restrict__ ewc,
                          const int* __restrict__ off, int2* __restrict__ csr2,
                          int* __restrict__ cnt2) {
  int node = blockIdx.x * 8 + threadIdx.y;
  int lane = threadIdx.x;
  int s0 = off[node], s1 = off[node + 1];
  unsigned long long lt = ((unsigned long long)1 << lane) - 1;
  int cum = 0;
  for (int i0 = s0; i0 < s1; i0 += 64) {
    int i = i0 + lane;
    bool f = (i < s1) && sel[i];
    unsigned long long m = __ballot(f);
    if (f) {
      int rank = __popcll(m & lt);
      int2 se = csr[i];
      csr2[s0 + cum + rank] = make_int2(se.x, __float_as_int(ewc[i]));
    }
    cum += __popcll(m);
  }
  if (lane == 0) cnt2[node] = cum;
}

// ---- weighted aggregation over COMPACTED edges (bf16 rows): eighth-wave ----
__global__ void k_agg_w(const __hip_bfloat16* __restrict__ y, const float* __restrict__ r,
                        const int2* __restrict__ csr2, const int* __restrict__ cnt2,
                        const int* __restrict__ off, float* __restrict__ out) {
  int node = blockIdx.x * 8 + threadIdx.y;
  int lane = threadIdx.x;
  int q = lane >> 3, c = lane & 7;
  int b0 = off[node], cn = cnt2[node];
  float a[8] = {0.f, 0.f, 0.f, 0.f, 0.f, 0.f, 0.f, 0.f};
  for (int j = q; j < cn; j += 8) {
    int2 sw = csr2[b0 + j];
    float w = __int_as_float(sw.y);
    uint4 pk = ((const uint4*)((const unsigned short*)y + (size_t)sw.x * H))[c];
    a[0] += w * __uint_as_float(pk.x << 16); a[1] += w * __uint_as_float(pk.x & 0xffff0000u);
    a[2] += w * __uint_as_float(pk.y << 16); a[3] += w * __uint_as_float(pk.y & 0xffff0000u);
    a[4] += w * __uint_as_float(pk.z << 16); a[5] += w * __uint_as_float(pk.z & 0xffff0000u);
    a[6] += w * __uint_as_float(pk.w << 16); a[7] += w * __uint_as_float(pk.w & 0xffff0000u);
  }
#pragma unroll
  for (int d = 8; d < 64; d <<= 1) {
#pragma unroll
    for (int j = 0; j < 8; ++j) a[j] += __shfl_xor(a[j], d);
  }
  if (q == 0) {
    int degn = off[node + 1] - off[node];
    float inv = 1.f / fmaxf((float)degn, 1.f);
    const float4* rp = (const float4*)(r + (size_t)node * H);
    float4 r0 = rp[2 * c], r1 = rp[2 * c + 1];
    float4 o0, o1;
    o0.x = fmaxf(a[0] * inv + r0.x, 0.f); o0.y = fmaxf(a[1] * inv + r0.y, 0.f);
    o0.z = fmaxf(a[2] * inv + r0.z, 0.f); o0.w = fmaxf(a[3] * inv + r0.w, 0.f);
    o1.x = fmaxf(a[4] * inv + r1.x, 0.f); o1.y = fmaxf(a[5] * inv + r1.y, 0.f);
    o1.z = fmaxf(a[6] * inv + r1.z, 0.f); o1.w = fmaxf(a[7] * inv + r1.w, 0.f);
    float4* op = (float4*)(out + (size_t)node * H);
    op[2 * c] = o0; op[2 * c + 1] = o1;
  }
}

// ---- node-major edge scoring in CSR order (x2 edge ILP) ----
__global__ void k_score_csr(const float* __restrict__ h1, const int2* __restrict__ csr,
                            const int* __restrict__ off, const int* __restrict__ batch,
                            unsigned* __restrict__ scoreu_csr,
                            unsigned short* __restrict__ seg_csr, int* __restrict__ hist) {
  int node = blockIdx.x * 8 + threadIdx.y;
  int lane = threadIdx.x;
  int q = lane >> 4, c = lane & 15;   // 4 quarters x 16 lanes; 16 x float4 = 256B row
  int s0 = off[node], s1 = off[node + 1];
  float4 hn = ((const float4*)(h1 + (size_t)node * H))[c];
  int i = s0 + q;
  for (; i + 4 < s1; i += 8) {
    int2 se0 = csr[i];
    int2 se1 = csr[i + 4];
    float4 hs0 = ((const float4*)(h1 + (size_t)se0.x * H))[c];
    float4 hs1 = ((const float4*)(h1 + (size_t)se1.x * H))[c];
    float p0 = hn.x * hs0.x + hn.y * hs0.y + hn.z * hs0.z + hn.w * hs0.w;
    float p1 = hn.x * hs1.x + hn.y * hs1.y + hn.z * hs1.z + hn.w * hs1.w;
    p0 += __shfl_xor(p0, 1); p1 += __shfl_xor(p1, 1);
    p0 += __shfl_xor(p0, 2); p1 += __shfl_xor(p1, 2);
    p0 += __shfl_xor(p0, 4); p1 += __shfl_xor(p1, 4);
    p0 += __shfl_xor(p0, 8); p1 += __shfl_xor(p1, 8);
    if (c == 0) {
      int g0 = batch[se0.x], g1 = batch[se1.x];
      unsigned u0 = __float_as_uint(p0); u0 = (u0 & 0x80000000u) ? ~u0 : (u0 | 0x80000000u);
      unsigned u1 = __float_as_uint(p1); u1 = (u1 & 0x80000000u) ? ~u1 : (u1 | 0x80000000u);
      scoreu_csr[i] = u0; scoreu_csr[i + 4] = u1;
      seg_csr[i] = (unsigned short)g0; seg_csr[i + 4] = (unsigned short)g1;
      atomicAdd(&hist[g0 * 256 + (int)(u0 >> 24)], 1);
      atomicAdd(&hist[g1 * 256 + (int)(u1 >> 24)], 1);
    }
  }
  for (; i < s1; i += 4) {
    int2 se = csr[i];
    float4 hs = ((const float4*)(h1 + (size_t)se.x * H))[c];
    float p = hn.x * hs.x + hn.y * hs.y + hn.z * hs.z + hn.w * hs.w;
    p += __shfl_xor(p, 1);
    p += __shfl_xor(p, 2);
    p += __shfl_xor(p, 4);
    p += __shfl_xor(p, 8);
    if (c == 0) {
      int g = batch[se.x];
      unsigned u = __float_as_uint(p);
      u = (u & 0x80000000u) ? ~u : (u | 0x80000000u);
      scoreu_csr[i] = u;
      seg_csr[i] = (unsigned short)g;
      atomicAdd(&hist[g * 256 + (int)(u >> 24)], 1);
    }
  }
}

// ---- radix-select histogram for passes 1..2 ----
__global__ void k_hist(const unsigned* __restrict__ scoreu, const unsigned short* __restrict__ seg,
                       const unsigned* __restrict__ prefix, int* __restrict__ hist, int pass) {
  int e = blockIdx.x * 256 + threadIdx.x;
  if (e >= E) return;
  unsigned u = scoreu[e];
  int g = (int)seg[e];
  int predshift = 32 - 8 * pass;
  if ((u >> predshift) == (prefix[g] >> predshift))
    atomicAdd(&hist[g * 256 + (int)((u >> (24 - 8 * pass)) & 0xFFu)], 1);
}

// ---- descending bucket select: one wave per graph; m from hist row sum ----
__global__ void k_scan(int* __restrict__ hist, unsigned* __restrict__ prefix,
                       int* __restrict__ krem, int pass) {
  int g = blockIdx.x;
  int lane = threadIdx.x;
  int4* row = (int4*)(hist + (size_t)g * 256);
  int4 v = row[lane];
  int vj[4] = {v.x, v.y, v.z, v.w};
  int s = v.x + v.y + v.z + v.w;
  int inc = s;
  for (int d = 1; d < 64; d <<= 1) {
    int t = __shfl_up(inc, d);
    if (lane >= d) inc += t;
  }
  int T = __shfl(inc, 63);
  int k = (pass == 0) ? ((T + 1) >> 1) : krem[g];   // pass 0: T = edges in graph
  int excl = inc - s;
  int pre[4] = {excl, excl + vj[0], excl + vj[0] + vj[1], excl + vj[0] + vj[1] + vj[2]};
  int bsel_l = -1, newk_l = 0;
  if (k > 0) {
    for (int j = 3; j >= 0; --j) {
      int suf = T - pre[j];
      if (suf >= k) { bsel_l = 4 * lane + j; newk_l = k - (suf - vj[j]); break; }
    }
  }
  unsigned long long mask = __ballot(bsel_l >= 0);
  int bsel = 255, newk = 0;
  if (k > 0 && mask) {
    int hi = 63 - __builtin_clzll(mask);
    bsel = __shfl(bsel_l, hi);
    newk = __shfl(newk_l, hi);
  }
  if (lane == 0) {
    unsigned base = (pass == 0) ? 0u : prefix[g];
    prefix[g] = base | ((unsigned)bsel << (24 - 8 * pass));
    krem[g] = newk;
  }
  row[lane] = make_int4(0, 0, 0, 0);
}

// ---- classify CSR slots vs 24-bit threshold ----
__global__ void k_select(const unsigned* __restrict__ scoreu_csr,
                         const unsigned short* __restrict__ seg_csr,
                         const unsigned* __restrict__ thresh,
                         int* __restrict__ eqcnt, int* __restrict__ eqlist,
                         unsigned char* __restrict__ sel_csr, float* __restrict__ ew_csr) {
  int s = blockIdx.x * 256 + threadIdx.x;
  if (s >= E) return;
  unsigned u = scoreu_csr[s];
  int g = (int)seg_csr[s];
  unsigned t = thresh[g];                 // top-24 bits, low 8 zero
  unsigned um = u & 0xffffff00u;
  float sel = 0.f;
  if (um > t) sel = 1.f;
  else if (um == t) {
    int slot = atomicAdd(&eqcnt[g], 1);
    if (slot < CAP) eqlist[g * CAP + slot] = s;
  }
  sel_csr[s] = (unsigned char)sel;
  ew_csr[s] = uinv_score(u) * sel;
}

// ---- resolve 24-bit ties: top-r by (score desc, original idx asc); r,c ~1-3 ----
__global__ void k_resolve(const int* __restrict__ krem, const int* __restrict__ eqcnt,
                          const int* __restrict__ eqlist, const int2* __restrict__ csr,
                          const unsigned* __restrict__ scoreu_csr,
                          unsigned char* __restrict__ sel_csr, float* __restrict__ ew_csr) {
  int g = blockIdx.x * 256 + threadIdx.x;
  if (g >= G) return;
  int c = eqcnt[g]; if (c > CAP) c = CAP;
  int r = krem[g];  if (r > c) r = c;
  const int* lst = eqlist + g * CAP;
  unsigned last_u = 0u; int last_e = -1; bool first = true;
  for (int i = 0; i < r; ++i) {
    unsigned bu = 0u; int be = -1, bs = -1;
    for (int j = 0; j < c; ++j) {
      int slot = lst[j];
      unsigned u = scoreu_csr[slot];
      int eid = csr[slot].y;
      bool after = first || (u < last_u) || (u == last_u && eid > last_e);
      if (after && (bs < 0 || u > bu || (u == bu && eid < be))) { bu = u; be = eid; bs = slot; }
    }
    if (bs < 0) break;
    sel_csr[bs] = 1;
    ew_csr[bs] = uinv_score(bu);
    last_u = bu; last_e = be; first = false;
  }
}

// ---- back-permute selection flags to edge order (output), x4 vectorized ----
__global__ void k_sampled(const int* __restrict__ einv, const unsigned char* __restrict__ sel_csr,
                          float* __restrict__ sampled) {
  int e = (blockIdx.x * 256 + threadIdx.x) * 4;
  if (e >= E) return;
  int4 iv = *(const int4*)(einv + e);
  float4 o;
  o.x = (float)sel_csr[iv.x];
  o.y = (float)sel_csr[iv.y];
  o.z = (float)sel_csr[iv.z];
  o.w = (float)sel_csr[iv.w];
  *(float4*)(sampled + e) = o;
}

// ---- fused mean-pool + MLP head + log_softmax: one block per graph ----
__global__ void k_poolhead(const float* __restrict__ h3, const int* __restrict__ goff,
                           const float* __restrict__ W1, const float* __restrict__ b1,
                           const float* __restrict__ W2, const float* __restrict__ b2,
                           float* __restrict__ outp) {
  int g = blockIdx.x;
  int h = threadIdx.x;
  int s0 = goff[g], s1 = goff[g + 1];
  float a = 0.f;
  for (int n = s0; n < s1; ++n) a += h3[(size_t)n * H + h];
  float inv = 1.f / fmaxf((float)(s1 - s0), 1.f);
  __shared__ float p[H], z1[H], z2[C];
  __shared__ float lse;
  p[h] = a * inv;
  __syncthreads();
  float acc = b1[h];
#pragma unroll 8
  for (int f = 0; f < H; ++f) acc += p[f] * W1[f * H + h];
  z1[h] = fmaxf(acc, 0.f);
  __syncthreads();
  if (h < C) {
    float a2 = b2[h];
#pragma unroll 8
    for (int f = 0; f < H; ++f) a2 += z1[f] * W2[f * C + h];
    z2[h] = a2;
  }
  __syncthreads();
  if (h == 0) {
    float m = z2[0];
    for (int c = 1; c < C; ++c) m = fmaxf(m, z2[c]);
    float s = 0.f;
    for (int c = 0; c < C; ++c) s += expf(z2[c] - m);
    lse = m + logf(s);
  }
  __syncthreads();
  if (h < C) outp[(size_t)g * C + h] = z2[h] - lse;
}

extern "C" void kernel_launch(void* const* d_in, const int* in_sizes, int n_in,
                              void* d_out, int out_size, void* d_ws, size_t ws_size,
                              hipStream_t stream) {
  const float* x     = (const float*)d_in[0];
  const int*   ei    = (const int*)d_in[1];
  const int*   batch = (const int*)d_in[2];
  const float* W1l   = (const float*)d_in[3];
  const float* b1l   = (const float*)d_in[4];
  const float* W1r   = (const float*)d_in[5];
  const float* W2l   = (const float*)d_in[6];
  const float* b2l   = (const float*)d_in[7];
  const float* W2r   = (const float*)d_in[8];
  const float* W3l   = (const float*)d_in[9];
  const float* b3l   = (const float*)d_in[10];
  const float* W3r   = (const float*)d_in[11];
  const float* Wlin1 = (const float*)d_in[12];
  const float* blin1 = (const float*)d_in[13];
  const float* Wlin2 = (const float*)d_in[14];
  const float* blin2 = (const float*)d_in[15];

  const int* srcv = ei;        // edge_index row 0
  const int* dstv = ei + E;    // edge_index row 1

  float* out_ls   = (float*)d_out;       // 512*10 log_softmax
  float* out_samp = out_ls + G * C;      // 800000 sampled mask

  // ---- workspace carve (256B-aligned); zero-init block first, one memset ----
  char* w = (char*)d_ws;
  auto carve = [&](size_t bytes) { void* p = (void*)w; w += (bytes + 255) & ~(size_t)255; return p; };
  char* zbase   = w;
  int*      deg     = (int*)carve((size_t)N * 4);
  int*      eqcnt   = (int*)carve((size_t)G * 4);
  int*      hist    = (int*)carve((size_t)G * 256 * 4);
  size_t    zbytes  = (size_t)(w - zbase);
  float*    h1      = (float*)carve((size_t)N * H * 4);
  float*    h2      = (float*)carve((size_t)N * H * 4);
  float*    h3      = (float*)carve((size_t)N * H * 4);
  float*    yb      = (float*)carve((size_t)N * H * 4);   // fp32 projected-left (layer 1)
  float*    rb      = (float*)carve((size_t)N * H * 4);   // fp32 projected-right
  __hip_bfloat16* ybh = (__hip_bfloat16*)carve((size_t)N * H * 2);  // bf16 table (layers 2/3)
  unsigned* scoreu_csr = (unsigned*)carve((size_t)E * 4);
  unsigned short* seg_csr = (unsigned short*)carve((size_t)E * 2);
  float*    ew_csr     = (float*)carve((size_t)E * 4);
  unsigned char* sel_csr = (unsigned char*)carve((size_t)E);
  int2*     csr     = (int2*)carve((size_t)E * 8);        // {src, eid} per slot
  int*      einv    = (int*)carve((size_t)E * 4);         // edge -> slot
  int*      off     = (int*)carve((size_t)(N + 1) * 4);
  int*      cursor  = (int*)carve((size_t)N * 4);
  int*      cnt2    = (int*)carve((size_t)N * 4);
  int*      goff    = (int*)carve((size_t)(G + 1) * 4);
  unsigned* prefix  = (unsigned*)carve((size_t)G * 4);
  int*      krem    = (int*)carve((size_t)G * 4);
  int*      eqlist  = (int*)carve((size_t)G * CAP * 4);
  int*      bsum    = (int*)carve((size_t)16 * 4);
  int2*     csr2    = (int2*)carve((size_t)E * 8);        // compacted {src, w} at off[node]

  hipMemsetAsync(zbase, 0, zbytes, stream);

  // ---- deg + goff, parallel scan, 2-window CSR fill ----
  k_deg_goff<<<128, 256, 0, stream>>>(dstv, batch, deg, goff);
  int nb = cdiv(N, 4096);   // 13
  k_scan_a<<<nb, 1024, 0, stream>>>(deg, off, bsum, N);
  k_scan_b<<<1, 64, 0, stream>>>(bsum, nb);
  k_scan_c<<<cdiv(N + 1, 256), 256, 0, stream>>>(off, cursor, bsum, N, nb);
  k_fill_csr<<<cdiv(E, 256), 256, 0, stream>>>(srcv, dstv, cursor, csr, einv, 0, N / 2);
  k_fill_csr<<<cdiv(E, 256), 256, 0, stream>>>(srcv, dstv, cursor, csr, einv, N / 2, N);

  // ---- layer 1: dense projections then fp32 gather ----
  k_gemm2<F><<<N / 16, dim3(64, 4), 0, stream>>>(x, W1l, W1r, b1l, yb, rb);
  k_agg1<<<N / 8, dim3(64, 8), 0, stream>>>(yb, rb, csr, off, h1);

  // ---- edge scores (CSR order) + 3-pass radix top-k (24-bit threshold) ----
  k_score_csr<<<N / 8, dim3(64, 8), 0, stream>>>(h1, csr, off, batch,
                                                 scoreu_csr, seg_csr, hist);
  k_scan<<<G, 64, 0, stream>>>(hist, prefix, krem, 0);
  for (int p = 1; p <= 2; ++p) {
    k_hist<<<cdiv(E, 256), 256, 0, stream>>>(scoreu_csr, seg_csr, prefix, hist, p);
    k_scan<<<G, 64, 0, stream>>>(hist, prefix, krem, p);
  }
  k_select<<<cdiv(E, 256), 256, 0, stream>>>(scoreu_csr, seg_csr, prefix,
                                             eqcnt, eqlist, sel_csr, ew_csr);
  k_resolve<<<cdiv(G, 256), 256, 0, stream>>>(krem, eqcnt, eqlist, csr, scoreu_csr,
                                              sel_csr, ew_csr);
  k_sampled<<<cdiv(E / 4, 256), 256, 0, stream>>>(einv, sel_csr, out_samp);

  // ---- compact selected edges per node at base off[node] (no atomics) ----
  k_compact<<<N / 8, dim3(64, 8), 0, stream>>>(sel_csr, csr, ew_csr, off, csr2, cnt2);

  // ---- layer 2: projections (bf16 gather table) + compacted weighted gather ----
  k_gemm2h<H><<<N / 16, dim3(64, 4), 0, stream>>>(h1, W2l, W2r, b2l, ybh, rb);
  k_agg_w<<<N / 8, dim3(64, 8), 0, stream>>>(ybh, rb, csr2, cnt2, off, h2);

  // ---- layer 3 ----
  k_gemm2h<H><<<N / 16, dim3(64, 4), 0, stream>>>(h2, W3l, W3r, b3l, ybh, rb);
  k_agg_w<<<N / 8, dim3(64, 8), 0, stream>>>(ybh, rb, csr2, cnt2, off, h3);

  // ---- fused pool + head ----
  k_poolhead<<<G, 64, 0, stream>>>(h3, goff, Wlin1, blin1, Wlin2, blin2, out_ls);
}